// Round 13
// baseline (443.818 us; speedup 1.0000x reference)
//
#include <hip/hip_runtime.h>
#include <type_traits>

// Problem constants (from reference):
//   B=100000, R1=1, N1=200, N2=200, N3=50, R2=32
//   TT_core: (1,200,200,50,32) f32  = 64,000,000 elems (256 MB)
//   K1,K2: (200,200) f32; K3: (50,50) f32; indices: (B,3) int (values in [0,50))
//   out = (T3 gathered)[B,1,32] (3.2M f32), reg = T3*TT (64M f32)
// d_out layout: [0,3.2M) out, [3.2M, 67.2M) reg.
//
// Round-13: barrier-minimal contraction. Round-12 evidence: ci/cj stuck at
// 161us with ALL pipes <12% busy regardless of B source (HBM vs L3) -> the
// 7x{ALOAD/ds_write/barrier+drain} stage machinery IS the critical path
// (conflict fix was null = T2-null-at-2phase, m252). Now: A staged in TWO
// phases into one 53KB buffer (208x128 halves, 3 blocks/CU); 3 barriers
// total; stages run back-to-back with zero mid-stage drains; B all-prefetch
// kept (single drain at barrier 1). Chunk swizzle kept (2-way = free).

typedef float    f32x4 __attribute__((ext_vector_type(4)));
typedef float    f32x8 __attribute__((ext_vector_type(8)));
typedef _Float16 half8 __attribute__((ext_vector_type(8)));
typedef unsigned short ushort8 __attribute__((ext_vector_type(8)));
typedef unsigned short u16;
typedef unsigned int   u32;

#define N12   200
#define N3    50
#define R2    32
#define SJK   320000          // stride of i in TT == N2*N3*R2; also stride of a in T1
#define SKS   1600            // stride of j / b  == N3*R2
#define NTOT  64000000
#define OUT_ELEMS 3200000     // B*32
#define APAD  208             // padded rows of K matrices (13 * 16)
#define KPAD  224             // padded contraction dim (7 * 32)
#define K3B_HALVES 4096       // 2 kstep * 4 csub * 64 lane * 8 e

// ---------------- prep: K1,K2 -> padded fp16 [208][224]; K3 -> B-frag pack --
// kh: K1 at 0, K2 at APAD*KPAD, K3B (fragment-ordered fp16) at 2*APAD*KPAD.
__global__ __launch_bounds__(256) void k_prep(
    const float* __restrict__ K1, const float* __restrict__ K2,
    const float* __restrict__ K3, u16* __restrict__ kh) {
  int t = blockIdx.x * 256 + threadIdx.x;
  const int total = APAD * KPAD;
  if (t >= 2 * total + K3B_HALVES) return;
  float x;
  if (t < 2 * total) {
    const float* src = (t < total) ? K1 : K2;
    int tt = (t < total) ? t : t - total;
    int r = tt / KPAD, c = tt % KPAD;
    x = (r < N12 && c < N12) ? src[r * N12 + c] : 0.f;
  } else {
    int u = t - 2 * total;
    int e = u & 7, l = (u >> 3) & 63, frag = u >> 9;   // frag = kstep*4+csub
    int c = (frag & 3) * 16 + (l & 15);
    int k = (frag >> 2) * 32 + (l >> 4) * 8 + e;
    x = (c < N3 && k < N3) ? K3[c * N3 + k] : 0.f;
  }
  kh[t] = __builtin_bit_cast(u16, (_Float16)x);
}

// ---------------- MFMA contraction: D[row,n] = sum_k K[row,k] * B[k,n] -----
// Templated on B element type (float: cvt at stage; u16: raw fp16) and D
// element type (float / u16-fp16 store). A lives in ONE 53KB LDS buffer,
// filled in two phases (k 0..127, then k 128..223); B fully prefetched in
// regs (single vmcnt drain at barrier 1). 3 barriers total, no per-stage
// staging. LDS row stride 128 halves; logical 16B chunk c of row r stored
// at physical chunk (c + (r>>1)) & 3 (2-way residual conflict = free).
#define LOADB(S, BV)                                                          \
  { _Pragma("unroll")                                                         \
    for (int e = 0; e < 8; ++e) {                                             \
      int kr = (S)*32 + kq + e; if (kr > 199) kr = 199;                       \
      BV[e] = bp[(long)kr * ldB]; } }

#define STAGE(SL, BV)                                                         \
  { half8 bh;                                                                 \
    _Pragma("unroll")                                                         \
    for (int e = 0; e < 8; ++e) {                                             \
      if constexpr (BF32) bh[e] = (_Float16)BV[e];                            \
      else bh[e] = __builtin_bit_cast(_Float16, (u16)BV[e]);                  \
    }                                                                         \
    _Pragma("unroll")                                                         \
    for (int t = 0; t < 13; ++t) {                                            \
      half8 ah = *(const half8*)(As + (t*16 + l15)*128 + (SL)*32 + rdc);      \
      acc[t] = __builtin_amdgcn_mfma_f32_16x16x32_f16(ah, bh, acc[t], 0,0,0); \
    } }

template <typename BT, typename DT>
__global__ __launch_bounds__(256, 3) void k_mfma_contract(
    const BT* __restrict__ Bsrc, const u16* __restrict__ Ah,
    DT* __restrict__ Dout, int ldB, int ldD, long bStrideB, long bStrideD) {
  constexpr bool BF32 = std::is_same_v<BT, float>;
  __shared__ __align__(16) u16 As[APAD * 128];   // 53,248 B -> 3 blocks/CU
  const int tid  = threadIdx.x;
  const int lane = tid & 63;
  const int wave = tid >> 6;
  const int l15  = lane & 15;
  const int kg   = lane >> 4;
  const int kq   = kg * 8;
  const int rdc  = ((kg + (l15 >> 1)) & 3) * 8;   // read-side swizzle const
  const int n0   = blockIdx.x * 64 + wave * 16 + l15;
  const long bb  = (long)blockIdx.y * bStrideB;
  const long db  = (long)blockIdx.y * bStrideD;
  const BT* bp = Bsrc + bb + n0;

  f32x4 acc[13];
#pragma unroll
  for (int t = 0; t < 13; ++t)
#pragma unroll
    for (int q = 0; q < 4; ++q) acc[t][q] = 0.f;

  using BReg = std::conditional_t<BF32, f32x8, ushort8>;
  BReg B0, B1, B2, B3, B4, B5, B6;

  // ---- phase-1 A coop load: k-slices 0-3 (3328 int4, 13/thread exact) ----
#pragma unroll
  for (int it = 0; it < 13; ++it) {
    int u = tid + it * 256;
    int row = u >> 4, c16 = u & 15;        // c16 = sl*4 + c4, cols 0..127
    int sl = c16 >> 2, c4 = c16 & 3;
    int4 v = *(const int4*)(Ah + row * KPAD + c16 * 8);
    *(int4*)(&As[row * 128 + sl * 32 + ((c4 + (row >> 1)) & 3) * 8]) = v;
  }
  // ---- B prefetch: ALL 7 stages; single drain at the barrier below ----
  LOADB(0, B0) LOADB(1, B1) LOADB(2, B2) LOADB(3, B3)
  LOADB(4, B4) LOADB(5, B5) LOADB(6, B6)
  __syncthreads();

  STAGE(0, B0)  STAGE(1, B1)  STAGE(2, B2)  STAGE(3, B3)
  __syncthreads();

  // ---- phase-2 A coop load: k-slices 4-6 into slice slots 0-2 (L2-hot) ----
  for (int u = tid; u < APAD * 12; u += 256) {
    int row = u / 12, c12 = u - row * 12;  // cols 128..223
    int sl = c12 >> 2, c4 = c12 & 3;
    int4 v = *(const int4*)(Ah + row * KPAD + 128 + c12 * 8);
    *(int4*)(&As[row * 128 + sl * 32 + ((c4 + (row >> 1)) & 3) * 8]) = v;
  }
  __syncthreads();

  STAGE(0, B4)  STAGE(1, B5)  STAGE(2, B6)

#pragma unroll
  for (int t = 0; t < 13; ++t) {
    const int rb = t * 16 + kg * 4;
#pragma unroll
    for (int r = 0; r < 4; ++r) {
      const int row = rb + r;
      if (row < N12) {
        if constexpr (std::is_same_v<DT, float>)
          Dout[db + (long)row * ldD + n0] = acc[t][r];
        else
          Dout[db + (long)row * ldD + n0] =
              __builtin_bit_cast(u16, (_Float16)acc[t][r]);
      }
    }
  }
}

// ------- contract k + elementwise, MFMA form (fp16 T2 input) --------------
// Per wave: one ab. D[s,c] = sum_k T2[ab,k,s]*K3[c,k]; B = K3B frags (LDS).
// Epilogue: cs OUTER, both rt halves of each 128B line stored back-to-back
// (round-9: rt-outer spread the halves -> 1.64x write amplification).
__global__ __launch_bounds__(256, 8) void k_contract_k_mfma(
    const u16* __restrict__ T2h, const float* __restrict__ TT,
    const u16* __restrict__ K3B, float* __restrict__ reg) {
  __shared__ __align__(16) u16 bs[K3B_HALVES];   // 8 KB
  const int tid  = threadIdx.x;
  {
    const int4* src = (const int4*)K3B;
    int4* dst = (int4*)bs;
    dst[tid] = src[tid];
    dst[tid + 256] = src[tid + 256];
  }
  const int lane = tid & 63;
  const int wave = tid >> 6;
  const int l15  = lane & 15;
  const int kg   = lane >> 4;
  const int ab   = blockIdx.x * 4 + wave;         // 0..39999
  const int base = ab * SKS;
  __syncthreads();

  half8 bf[2][4];
#pragma unroll
  for (int ks = 0; ks < 2; ++ks)
#pragma unroll
    for (int cs = 0; cs < 4; ++cs)
      bf[ks][cs] = *(const half8*)(bs + ((ks * 4 + cs) * 64 + lane) * 8);

  // A fragments: fp16 direct. k clamped (B rows >= 50 are zero-padded).
  half8 af[2][2];
#pragma unroll
  for (int rt = 0; rt < 2; ++rt)
#pragma unroll
    for (int ks = 0; ks < 2; ++ks)
#pragma unroll
      for (int e = 0; e < 8; ++e) {
        int k = ks * 32 + kg * 8 + e; if (k > 49) k = 49;
        af[rt][ks][e] =
            __builtin_bit_cast(_Float16, T2h[base + k * R2 + rt * 16 + l15]);
      }

  f32x4 acc[2][4];
#pragma unroll
  for (int rt = 0; rt < 2; ++rt)
#pragma unroll
    for (int cs = 0; cs < 4; ++cs)
#pragma unroll
      for (int q = 0; q < 4; ++q) acc[rt][cs][q] = 0.f;

#pragma unroll
  for (int rt = 0; rt < 2; ++rt)
#pragma unroll
    for (int ks = 0; ks < 2; ++ks)
#pragma unroll
      for (int cs = 0; cs < 4; ++cs)
        acc[rt][cs] = __builtin_amdgcn_mfma_f32_16x16x32_f16(
            af[rt][ks], bf[ks][cs], acc[rt][cs], 0, 0, 0);

  // epilogue: c = cs*16+l15 (valid < 50); per c, the full 128B line
  // (s 0..31) is covered by two adjacent dwordx4 stores issued back-to-back
  // so the line is fully dirty before any eviction window opens.
#pragma unroll
  for (int cs = 0; cs < 4; ++cs) {
    const int c = cs * 16 + l15;
    if (c < N3) {
      const int o0 = base + c * R2 + kg * 4;
      f32x4 tv0 = *(const f32x4*)(TT + o0);
      f32x4 tv1 = *(const f32x4*)(TT + o0 + 16);
      f32x4 r0, r1;
#pragma unroll
      for (int q = 0; q < 4; ++q) {
        r0[q] = acc[0][cs][q] * tv0[q];
        r1[q] = acc[1][cs][q] * tv1[q];
      }
      *(f32x4*)(reg + o0) = r0;
      *(f32x4*)(reg + o0 + 16) = r1;
    }
  }
}

// ------------- gather: out[n,s] = sum_k K3[c,k] * T2[a,b,k,s]  (a,b,c < 50)
template <typename T>
__global__ __launch_bounds__(256) void k_gather(
    const T* T2, const float* __restrict__ K3,
    const int* __restrict__ idx, float* __restrict__ out) {
  int g = blockIdx.x * 256 + threadIdx.x;   // 3.2M threads exactly
  int n = g >> 5, s = g & 31;
  int a = idx[n * 3 + 0], b = idx[n * 3 + 1], c = idx[n * 3 + 2];
  const T* t2 = T2 + a * SJK + b * SKS + s;
  const float* k3r = K3 + c * N3;
  float acc = 0.f;
#pragma unroll
  for (int k = 0; k < N3; ++k) {
    float v;
    if constexpr (std::is_same_v<T, float>) v = t2[k * R2];
    else v = (float)__builtin_bit_cast(_Float16, t2[k * R2]);
    acc = fmaf(k3r[k], v, acc);
  }
  out[g] = acc;
}

// ---------------- fallback path helpers (unused when ws >= 128 MB) ---------
__global__ __launch_bounds__(256) void k_transpose(
    const float* __restrict__ K2, float* __restrict__ K2T) {
  int t = blockIdx.x * 256 + threadIdx.x;
  if (t < N12 * N12) {
    int i = t / N12, a = t % N12;
    K2T[t] = K2[a * N12 + i];
  }
}

__global__ __launch_bounds__(256) void k_contract_j_inplace(
    float* T12, const float* __restrict__ K2T) {
  __shared__ float lds[N12 * 80];   // 64000 B
  const int a    = blockIdx.y;
  const int m0   = blockIdx.x * 80;
  const int base = a * SJK + m0;
  for (int t = threadIdx.x; t < N12 * 80; t += 256) {
    int j = t / 80, ml = t % 80;
    lds[t] = T12[base + j * SKS + ml];
  }
  __syncthreads();
  for (int o = threadIdx.x; o < N12 * 80; o += 256) {
    int b = o / 80, ml = o % 80;
    float acc = 0.f;
#pragma unroll 4
    for (int j = 0; j < N12; ++j)
      acc = fmaf(K2T[j * N12 + b], lds[j * 80 + ml], acc);
    T12[base + b * SKS + ml] = acc;
  }
}

__global__ __launch_bounds__(256) void k_contract_k_reg(
    const float* T2, const float* __restrict__ TT,
    const float* __restrict__ K3, float* reg) {
  const int t  = blockIdx.x * 256 + threadIdx.x;
  const int s  = t & 31;
  const int ab = t >> 5;
  const int base = ab * SKS + s;
  float v[N3];
#pragma unroll
  for (int k = 0; k < N3; ++k) v[k] = T2[base + k * R2];
  for (int c = 0; c < N3; ++c) {
    const float* k3r = K3 + c * N3;
    float a0 = 0.f, a1 = 0.f, a2 = 0.f, a3 = 0.f;
#pragma unroll
    for (int k = 0; k < 48; k += 4) {
      a0 = fmaf(k3r[k],     v[k],     a0);
      a1 = fmaf(k3r[k + 1], v[k + 1], a1);
      a2 = fmaf(k3r[k + 2], v[k + 2], a2);
      a3 = fmaf(k3r[k + 3], v[k + 3], a3);
    }
    a0 = fmaf(k3r[48], v[48], a0);
    a1 = fmaf(k3r[49], v[49], a1);
    const int o = base + c * R2;
    reg[o] = ((a0 + a1) + (a2 + a3)) * TT[o];
  }
}

extern "C" void kernel_launch(void* const* d_in, const int* in_sizes, int n_in,
                              void* d_out, int out_size, void* d_ws, size_t ws_size,
                              hipStream_t stream) {
  const float* TT  = (const float*)d_in[0];
  const float* K1  = (const float*)d_in[1];
  const float* K2  = (const float*)d_in[2];
  const float* K3  = (const float*)d_in[3];
  const int*   idx = (const int*)d_in[4];

  float* out = (float*)d_out;          // [0, 3.2M)
  float* reg = out + OUT_ELEMS;        // [3.2M, 67.2M) -- also T1h scratch
  // Prepped fp16 K matrices + K3B fragment pack live at the start of the out
  // region (dead before k_gather overwrites out).
  u16* kh = (u16*)d_out;
  const int matoff = APAD * KPAD;               // K2 offset within kh
  const u16* k3b = kh + 2 * matoff;             // K3B offset

  k_prep<<<dim3((2 * matoff + K3B_HALVES + 255) / 256), 256, 0, stream>>>(
      K1, K2, K3, kh);

  const size_t need = (size_t)NTOT * sizeof(u16);   // 128,000,000 B
  if (ws_size >= need) {
    u16* T1h = (u16*)reg;          // 128 MB in reg region (dead before ck)
    u16* T2h = (u16*)d_ws;         // 128 MB
    // contract i: T1h[a,m] = sum_i K1[a,i]*TT[i,m]
    k_mfma_contract<float, u16><<<dim3(SJK / 64, 1), 256, 0, stream>>>(
        TT, kh, T1h, SJK, SJK, 0L, 0L);
    // contract j (batched over a): T2h[a,b,m2] = sum_j K2[b,j]*T1h[a,j,m2]
    k_mfma_contract<u16, u16><<<dim3(SKS / 64, N12), 256, 0, stream>>>(
        T1h, kh + matoff, T2h, SKS, SKS, (long)SJK, (long)SJK);
    // contract k (writes reg fp32 over T1h region -- T1 dead; K3B still live)
    k_contract_k_mfma<<<dim3(40000 / 4), 256, 0, stream>>>(T2h, TT, k3b, reg);
    // gather last (clobbers kh/k3b region)
    k_gather<u16><<<dim3(OUT_ELEMS / 256), 256, 0, stream>>>(T2h, K3, idx, out);
  } else {
    // fp32 fallback (never taken on this harness: rounds 1-12 ran ws path)
    float* k2t = out + 2 * OUT_ELEMS / 32;  // scratch inside out region
    k_mfma_contract<float, float><<<dim3(SJK / 64, 1), 256, 0, stream>>>(
        TT, kh, reg, SJK, SJK, 0L, 0L);
    k_transpose<<<dim3((N12 * N12 + 255) / 256), 256, 0, stream>>>(K2, k2t);
    k_contract_j_inplace<<<dim3(20, N12), 256, 0, stream>>>(reg, k2t);
    k_gather<float><<<dim3(OUT_ELEMS / 256), 256, 0, stream>>>(reg, K3, idx, out);
    k_contract_k_reg<<<dim3(40000 * 32 / 256), 256, 0, stream>>>(reg, TT, K3, reg);
  }
}

// Round 14
// 431.427 us; speedup vs baseline: 1.0287x; 1.0287x over previous
//
#include <hip/hip_runtime.h>
#include <type_traits>

// Problem constants (from reference):
//   B=100000, R1=1, N1=200, N2=200, N3=50, R2=32
//   TT_core: (1,200,200,50,32) f32  = 64,000,000 elems (256 MB)
//   K1,K2: (200,200) f32; K3: (50,50) f32; indices: (B,3) int (values in [0,50))
//   out = (T3 gathered)[B,1,32] (3.2M f32), reg = T3*TT (64M f32)
// d_out layout: [0,3.2M) out, [3.2M, 67.2M) reg.
//
// Round-14: concurrency restructure of k_mfma_contract. R10-R13 invariant:
// ci/cj pinned at 160-175us, all pipes <20%, Occ 28% -> latency-bound with
// only 3 blocks/CU resident. Now: ONE 26.6KB LDS buffer ([208][64] halves),
// 4-phase A staging (fills 1-3 are L2-hot, ~250cyc drains; only barrier 1
// pays HBM latency), B cvt'd to half8 right after barrier 1 (frees 28 regs),
// launch_bounds(256,4) -> 4 blocks/CU. Swizzle: physical 16B chunk =
// (c8+row)&7 covers all 8 bank-quads (R13's 4-position swizzle was 4-way
// conflicted at 256B rows -> 22.4M conflicts).

typedef float    f32x4 __attribute__((ext_vector_type(4)));
typedef float    f32x8 __attribute__((ext_vector_type(8)));
typedef _Float16 half8 __attribute__((ext_vector_type(8)));
typedef unsigned short ushort8 __attribute__((ext_vector_type(8)));
typedef unsigned short u16;
typedef unsigned int   u32;

#define N12   200
#define N3    50
#define R2    32
#define SJK   320000          // stride of i in TT == N2*N3*R2; also stride of a in T1
#define SKS   1600            // stride of j / b  == N3*R2
#define NTOT  64000000
#define OUT_ELEMS 3200000     // B*32
#define APAD  208             // padded rows of K matrices (13 * 16)
#define KPAD  224             // padded contraction dim (7 * 32)
#define K3B_HALVES 4096       // 2 kstep * 4 csub * 64 lane * 8 e

// ---------------- prep: K1,K2 -> padded fp16 [208][224]; K3 -> B-frag pack --
// kh: K1 at 0, K2 at APAD*KPAD, K3B (fragment-ordered fp16) at 2*APAD*KPAD.
__global__ __launch_bounds__(256) void k_prep(
    const float* __restrict__ K1, const float* __restrict__ K2,
    const float* __restrict__ K3, u16* __restrict__ kh) {
  int t = blockIdx.x * 256 + threadIdx.x;
  const int total = APAD * KPAD;
  if (t >= 2 * total + K3B_HALVES) return;
  float x;
  if (t < 2 * total) {
    const float* src = (t < total) ? K1 : K2;
    int tt = (t < total) ? t : t - total;
    int r = tt / KPAD, c = tt % KPAD;
    x = (r < N12 && c < N12) ? src[r * N12 + c] : 0.f;
  } else {
    int u = t - 2 * total;
    int e = u & 7, l = (u >> 3) & 63, frag = u >> 9;   // frag = kstep*4+csub
    int c = (frag & 3) * 16 + (l & 15);
    int k = (frag >> 2) * 32 + (l >> 4) * 8 + e;
    x = (c < N3 && k < N3) ? K3[c * N3 + k] : 0.f;
  }
  kh[t] = __builtin_bit_cast(u16, (_Float16)x);
}

// ---------------- MFMA contraction: D[row,n] = sum_k K[row,k] * B[k,n] -----
// A in ONE [208][64] LDS buffer filled in 4 phases (cols 0-63,64-127,
// 128-191,192-223). Physical 16B chunk of row r = (c8 + r) & 7 -> reads and
// coop writes both spread over all 8 bank-quads (2/bank = free). B: all 7
// stages prefetched as fp32/u16 before phase-0 fill (fill's first wait
// implicitly drains B), converted to half8 once after barrier 1.
#define LOADB(S, BV)                                                          \
  { _Pragma("unroll")                                                         \
    for (int e = 0; e < 8; ++e) {                                             \
      int kr = (S)*32 + kq + e; if (kr > 199) kr = 199;                       \
      BV[e] = bp[(long)kr * ldB]; } }

#define CVTB(I, BV)                                                           \
  { _Pragma("unroll")                                                         \
    for (int e = 0; e < 8; ++e) {                                             \
      if constexpr (BF32) hb[I][e] = (_Float16)BV[e];                         \
      else hb[I][e] = __builtin_bit_cast(_Float16, (u16)BV[e]);               \
    } }

// fill phases 0-2: 1664 int4 (8 per row); phase 3: 832 int4 (4 per row)
#define FILLA(P)                                                              \
  { if ((P) < 3) {                                                            \
      for (int u = tid; u < 1664; u += 256) {                                 \
        int row = u >> 3, c8 = u & 7;                                         \
        int4 v = *(const int4*)(Ah + row * KPAD + (P)*64 + c8 * 8);           \
        *(int4*)(&As[row * 64 + ((c8 + row) & 7) * 8]) = v;                   \
      }                                                                       \
    } else {                                                                  \
      for (int u = tid; u < 832; u += 256) {                                  \
        int row = u >> 2, c4 = u & 3;                                         \
        int4 v = *(const int4*)(Ah + row * KPAD + 192 + c4 * 8);              \
        *(int4*)(&As[row * 64 + ((c4 + row) & 7) * 8]) = v;                   \
      }                                                                       \
    } }

#define STAGE(SL, I)                                                          \
  { _Pragma("unroll")                                                         \
    for (int t = 0; t < 13; ++t) {                                            \
      const int row = t * 16 + l15;                                           \
      half8 ah = *(const half8*)(As + row * 64 + (((SL)*4 + kg + row) & 7)*8);\
      acc[t] = __builtin_amdgcn_mfma_f32_16x16x32_f16(ah, hb[I], acc[t],      \
                                                      0, 0, 0);               \
    } }

template <typename BT, typename DT>
__global__ __launch_bounds__(256, 4) void k_mfma_contract(
    const BT* __restrict__ Bsrc, const u16* __restrict__ Ah,
    DT* __restrict__ Dout, int ldB, int ldD, long bStrideB, long bStrideD) {
  constexpr bool BF32 = std::is_same_v<BT, float>;
  __shared__ __align__(16) u16 As[APAD * 64];   // 26,624 B -> 6 blocks by LDS
  const int tid  = threadIdx.x;
  const int lane = tid & 63;
  const int wave = tid >> 6;
  const int l15  = lane & 15;
  const int kg   = lane >> 4;
  const int kq   = kg * 8;
  const int n0   = blockIdx.x * 64 + wave * 16 + l15;
  const long bb  = (long)blockIdx.y * bStrideB;
  const long db  = (long)blockIdx.y * bStrideD;
  const BT* bp = Bsrc + bb + n0;

  using BReg = std::conditional_t<BF32, f32x8, ushort8>;
  BReg B0, B1, B2, B3, B4, B5, B6;

  // B first (issues immediately), then phase-0 fill (its first vmcnt wait
  // implicitly drains the B stream -- the ONLY HBM-latency wait per block).
  LOADB(0, B0) LOADB(1, B1) LOADB(2, B2) LOADB(3, B3)
  LOADB(4, B4) LOADB(5, B5) LOADB(6, B6)
  FILLA(0)
  __syncthreads();

  half8 hb[7];
  CVTB(0, B0) CVTB(1, B1) CVTB(2, B2) CVTB(3, B3)
  CVTB(4, B4) CVTB(5, B5) CVTB(6, B6)

  f32x4 acc[13];
#pragma unroll
  for (int t = 0; t < 13; ++t)
#pragma unroll
    for (int q = 0; q < 4; ++q) acc[t][q] = 0.f;

  STAGE(0, 0)  STAGE(1, 1)
  __syncthreads();
  FILLA(1)
  __syncthreads();
  STAGE(0, 2)  STAGE(1, 3)
  __syncthreads();
  FILLA(2)
  __syncthreads();
  STAGE(0, 4)  STAGE(1, 5)
  __syncthreads();
  FILLA(3)
  __syncthreads();
  STAGE(0, 6)

#pragma unroll
  for (int t = 0; t < 13; ++t) {
    const int rb = t * 16 + kg * 4;
#pragma unroll
    for (int r = 0; r < 4; ++r) {
      const int row = rb + r;
      if (row < N12) {
        if constexpr (std::is_same_v<DT, float>)
          Dout[db + (long)row * ldD + n0] = acc[t][r];
        else
          Dout[db + (long)row * ldD + n0] =
              __builtin_bit_cast(u16, (_Float16)acc[t][r]);
      }
    }
  }
}

// ------- contract k + elementwise, MFMA form (fp16 T2 input) --------------
// Per wave: one ab. D[s,c] = sum_k T2[ab,k,s]*K3[c,k]; B = K3B frags (LDS).
// Epilogue: cs OUTER, both rt halves of each 128B line stored back-to-back
// (round-9: rt-outer spread the halves -> 1.64x write amplification).
__global__ __launch_bounds__(256, 8) void k_contract_k_mfma(
    const u16* __restrict__ T2h, const float* __restrict__ TT,
    const u16* __restrict__ K3B, float* __restrict__ reg) {
  __shared__ __align__(16) u16 bs[K3B_HALVES];   // 8 KB
  const int tid  = threadIdx.x;
  {
    const int4* src = (const int4*)K3B;
    int4* dst = (int4*)bs;
    dst[tid] = src[tid];
    dst[tid + 256] = src[tid + 256];
  }
  const int lane = tid & 63;
  const int wave = tid >> 6;
  const int l15  = lane & 15;
  const int kg   = lane >> 4;
  const int ab   = blockIdx.x * 4 + wave;         // 0..39999
  const int base = ab * SKS;
  __syncthreads();

  half8 bf[2][4];
#pragma unroll
  for (int ks = 0; ks < 2; ++ks)
#pragma unroll
    for (int cs = 0; cs < 4; ++cs)
      bf[ks][cs] = *(const half8*)(bs + ((ks * 4 + cs) * 64 + lane) * 8);

  // A fragments: fp16 direct. k clamped (B rows >= 50 are zero-padded).
  half8 af[2][2];
#pragma unroll
  for (int rt = 0; rt < 2; ++rt)
#pragma unroll
    for (int ks = 0; ks < 2; ++ks)
#pragma unroll
      for (int e = 0; e < 8; ++e) {
        int k = ks * 32 + kg * 8 + e; if (k > 49) k = 49;
        af[rt][ks][e] =
            __builtin_bit_cast(_Float16, T2h[base + k * R2 + rt * 16 + l15]);
      }

  f32x4 acc[2][4];
#pragma unroll
  for (int rt = 0; rt < 2; ++rt)
#pragma unroll
    for (int cs = 0; cs < 4; ++cs)
#pragma unroll
      for (int q = 0; q < 4; ++q) acc[rt][cs][q] = 0.f;

#pragma unroll
  for (int rt = 0; rt < 2; ++rt)
#pragma unroll
    for (int ks = 0; ks < 2; ++ks)
#pragma unroll
      for (int cs = 0; cs < 4; ++cs)
        acc[rt][cs] = __builtin_amdgcn_mfma_f32_16x16x32_f16(
            af[rt][ks], bf[ks][cs], acc[rt][cs], 0, 0, 0);

  // epilogue: c = cs*16+l15 (valid < 50); per c, the full 128B line
  // (s 0..31) is covered by two adjacent dwordx4 stores issued back-to-back
  // so the line is fully dirty before any eviction window opens.
#pragma unroll
  for (int cs = 0; cs < 4; ++cs) {
    const int c = cs * 16 + l15;
    if (c < N3) {
      const int o0 = base + c * R2 + kg * 4;
      f32x4 tv0 = *(const f32x4*)(TT + o0);
      f32x4 tv1 = *(const f32x4*)(TT + o0 + 16);
      f32x4 r0, r1;
#pragma unroll
      for (int q = 0; q < 4; ++q) {
        r0[q] = acc[0][cs][q] * tv0[q];
        r1[q] = acc[1][cs][q] * tv1[q];
      }
      *(f32x4*)(reg + o0) = r0;
      *(f32x4*)(reg + o0 + 16) = r1;
    }
  }
}

// ------------- gather: out[n,s] = sum_k K3[c,k] * T2[a,b,k,s]  (a,b,c < 50)
template <typename T>
__global__ __launch_bounds__(256) void k_gather(
    const T* T2, const float* __restrict__ K3,
    const int* __restrict__ idx, float* __restrict__ out) {
  int g = blockIdx.x * 256 + threadIdx.x;   // 3.2M threads exactly
  int n = g >> 5, s = g & 31;
  int a = idx[n * 3 + 0], b = idx[n * 3 + 1], c = idx[n * 3 + 2];
  const T* t2 = T2 + a * SJK + b * SKS + s;
  const float* k3r = K3 + c * N3;
  float acc = 0.f;
#pragma unroll
  for (int k = 0; k < N3; ++k) {
    float v;
    if constexpr (std::is_same_v<T, float>) v = t2[k * R2];
    else v = (float)__builtin_bit_cast(_Float16, t2[k * R2]);
    acc = fmaf(k3r[k], v, acc);
  }
  out[g] = acc;
}

// ---------------- fallback path helpers (unused when ws >= 128 MB) ---------
__global__ __launch_bounds__(256) void k_transpose(
    const float* __restrict__ K2, float* __restrict__ K2T) {
  int t = blockIdx.x * 256 + threadIdx.x;
  if (t < N12 * N12) {
    int i = t / N12, a = t % N12;
    K2T[t] = K2[a * N12 + i];
  }
}

__global__ __launch_bounds__(256) void k_contract_j_inplace(
    float* T12, const float* __restrict__ K2T) {
  __shared__ float lds[N12 * 80];   // 64000 B
  const int a    = blockIdx.y;
  const int m0   = blockIdx.x * 80;
  const int base = a * SJK + m0;
  for (int t = threadIdx.x; t < N12 * 80; t += 256) {
    int j = t / 80, ml = t % 80;
    lds[t] = T12[base + j * SKS + ml];
  }
  __syncthreads();
  for (int o = threadIdx.x; o < N12 * 80; o += 256) {
    int b = o / 80, ml = o % 80;
    float acc = 0.f;
#pragma unroll 4
    for (int j = 0; j < N12; ++j)
      acc = fmaf(K2T[j * N12 + b], lds[j * 80 + ml], acc);
    T12[base + b * SKS + ml] = acc;
  }
}

__global__ __launch_bounds__(256) void k_contract_k_reg(
    const float* T2, const float* __restrict__ TT,
    const float* __restrict__ K3, float* reg) {
  const int t  = blockIdx.x * 256 + threadIdx.x;
  const int s  = t & 31;
  const int ab = t >> 5;
  const int base = ab * SKS + s;
  float v[N3];
#pragma unroll
  for (int k = 0; k < N3; ++k) v[k] = T2[base + k * R2];
  for (int c = 0; c < N3; ++c) {
    const float* k3r = K3 + c * N3;
    float a0 = 0.f, a1 = 0.f, a2 = 0.f, a3 = 0.f;
#pragma unroll
    for (int k = 0; k < 48; k += 4) {
      a0 = fmaf(k3r[k],     v[k],     a0);
      a1 = fmaf(k3r[k + 1], v[k + 1], a1);
      a2 = fmaf(k3r[k + 2], v[k + 2], a2);
      a3 = fmaf(k3r[k + 3], v[k + 3], a3);
    }
    a0 = fmaf(k3r[48], v[48], a0);
    a1 = fmaf(k3r[49], v[49], a1);
    const int o = base + c * R2;
    reg[o] = ((a0 + a1) + (a2 + a3)) * TT[o];
  }
}

extern "C" void kernel_launch(void* const* d_in, const int* in_sizes, int n_in,
                              void* d_out, int out_size, void* d_ws, size_t ws_size,
                              hipStream_t stream) {
  const float* TT  = (const float*)d_in[0];
  const float* K1  = (const float*)d_in[1];
  const float* K2  = (const float*)d_in[2];
  const float* K3  = (const float*)d_in[3];
  const int*   idx = (const int*)d_in[4];

  float* out = (float*)d_out;          // [0, 3.2M)
  float* reg = out + OUT_ELEMS;        // [3.2M, 67.2M) -- also T1h scratch
  // Prepped fp16 K matrices + K3B fragment pack live at the start of the out
  // region (dead before k_gather overwrites out).
  u16* kh = (u16*)d_out;
  const int matoff = APAD * KPAD;               // K2 offset within kh
  const u16* k3b = kh + 2 * matoff;             // K3B offset

  k_prep<<<dim3((2 * matoff + K3B_HALVES + 255) / 256), 256, 0, stream>>>(
      K1, K2, K3, kh);

  const size_t need = (size_t)NTOT * sizeof(u16);   // 128,000,000 B
  if (ws_size >= need) {
    u16* T1h = (u16*)reg;          // 128 MB in reg region (dead before ck)
    u16* T2h = (u16*)d_ws;         // 128 MB
    // contract i: T1h[a,m] = sum_i K1[a,i]*TT[i,m]
    k_mfma_contract<float, u16><<<dim3(SJK / 64, 1), 256, 0, stream>>>(
        TT, kh, T1h, SJK, SJK, 0L, 0L);
    // contract j (batched over a): T2h[a,b,m2] = sum_j K2[b,j]*T1h[a,j,m2]
    k_mfma_contract<u16, u16><<<dim3(SKS / 64, N12), 256, 0, stream>>>(
        T1h, kh + matoff, T2h, SKS, SKS, (long)SJK, (long)SJK);
    // contract k (writes reg fp32 over T1h region -- T1 dead; K3B still live)
    k_contract_k_mfma<<<dim3(40000 / 4), 256, 0, stream>>>(T2h, TT, k3b, reg);
    // gather last (clobbers kh/k3b region)
    k_gather<u16><<<dim3(OUT_ELEMS / 256), 256, 0, stream>>>(T2h, K3, idx, out);
  } else {
    // fp32 fallback (never taken on this harness: rounds 1-13 ran ws path)
    float* k2t = out + 2 * OUT_ELEMS / 32;  // scratch inside out region
    k_mfma_contract<float, float><<<dim3(SJK / 64, 1), 256, 0, stream>>>(
        TT, kh, reg, SJK, SJK, 0L, 0L);
    k_transpose<<<dim3((N12 * N12 + 255) / 256), 256, 0, stream>>>(K2, k2t);
    k_contract_j_inplace<<<dim3(20, N12), 256, 0, stream>>>(reg, k2t);
    k_gather<float><<<dim3(OUT_ELEMS / 256), 256, 0, stream>>>(reg, K3, idx, out);
    k_contract_k_reg<<<dim3(40000 * 32 / 256), 256, 0, stream>>>(reg, TT, K3, reg);
  }
}